// Round 1
// baseline (106.613 us; speedup 1.0000x reference)
//
#include <hip/hip_runtime.h>

#define TIN   4096
#define FIN   128
#define NB    64
#define FOUT  128
#define TOUT  6144
// per-batch ws layout (ints): [0,TIN) seg_start, [TIN,2TIN) tgt, [2TIN,3TIN) cum_end, [3TIN] n_segs, [3TIN+1] T_total
#define SEG_STRIDE (3 * TIN + 64)

// Hillis-Steele inclusive scan across 256 threads. Returns inclusive prefix; *total = grand sum.
__device__ __forceinline__ int block_scan_incl(int v, int tid, int* sh, int* total) {
    sh[tid] = v;
    __syncthreads();
#pragma unroll
    for (int d = 1; d < 256; d <<= 1) {
        int x = 0;
        if (tid >= d) x = sh[tid - d];
        __syncthreads();
        sh[tid] += x;
        __syncthreads();
    }
    int incl = sh[tid];
    *total = sh[255];
    __syncthreads();
    return incl;
}

__global__ __launch_bounds__(256) void seg_kernel(const int* __restrict__ mask,
                                                  int* __restrict__ ws) {
    __shared__ int seg_start_sh[TIN];
    __shared__ int tgt_sh[TIN];
    __shared__ int cum_sh[TIN];
    __shared__ int scan_sh[256];

    const int b = blockIdx.x;
    const int tid = threadIdx.x;
    const int* mrow = mask + (size_t)b * TIN;

    for (int i = tid; i < TIN; i += 256) { seg_start_sh[i] = 0; tgt_sh[i] = 0; }
    __syncthreads();

    // ---- Phase A: change flags -> seg ids -> segment starts; voiced count ----
    const int base = tid * 16;
    int m[16];
#pragma unroll
    for (int j = 0; j < 16; ++j) m[j] = mrow[base + j];
    const int prev = (base == 0) ? 0 : mrow[base - 1];

    int incl[16];
    int run = 0, vsum = 0;
#pragma unroll
    for (int j = 0; j < 16; ++j) {
        int c;
        if (base + j == 0) c = 1;
        else c = (m[j] != ((j == 0) ? prev : m[j - 1])) ? 1 : 0;
        run += c;
        incl[j] = run;
        vsum += m[j];
    }
    int total_segs;
    int sincl = block_scan_incl(run, tid, scan_sh, &total_segs);
    int off = sincl - run;
#pragma unroll
    for (int j = 0; j < 16; ++j) {
        int c = (j == 0) ? incl[0] : (incl[j] - incl[j - 1]);
        if (c) seg_start_sh[off + incl[j] - 1] = base + j;
    }
    int total_v;
    block_scan_incl(vsum, tid, scan_sh, &total_v);
    __syncthreads();

    const int n_segs = total_segs;

    // ---- Phase B: rates (match reference f32 op order) ----
    const float len_v = (float)total_v;
    const float len_uv = (float)TIN - len_v;
    const float ratiof = (float)(0.7 / 0.3);
    const bool both = (len_v > 0.f) && (len_uv > 0.f);
    float rv;
    if (both)              rv = (float)TOUT / (len_v + len_uv / ratiof);
    else if (len_v > 0.f)  rv = (float)TOUT / fmaxf(len_v, 1.f);
    else                   rv = (float)TOUT / fmaxf(len_uv, 1.f);
    const float ruv = both ? (rv / ratiof) : rv;

    // ---- Phase C: per-segment target lengths (last takes remainder) ----
    int lsum = 0;
    for (int s = tid; s < n_segs; s += 256) {
        int st = seg_start_sh[s];
        int en = (s + 1 < n_segs) ? seg_start_sh[s + 1] : TIN;
        int len = en - st;
        bool voiced = (mrow[st] != 0);
        float scale = voiced ? rv : ruv;
        int tg = (int)fmaxf(1.0f, rintf(scale * (float)len));  // rintf == round-half-even == jnp.round
        if (s != n_segs - 1) { tgt_sh[s] = tg; lsum += tg; }
    }
    int sum_others;
    block_scan_incl(lsum, tid, scan_sh, &sum_others);
    if (tid == 0) tgt_sh[n_segs - 1] = max(1, TOUT - sum_others);
    __syncthreads();

    // ---- Phase D: inclusive scan of tgt -> cum_end ----
    int tincl[16];
    int trun = 0;
#pragma unroll
    for (int j = 0; j < 16; ++j) { trun += tgt_sh[base + j]; tincl[j] = trun; }
    int ttot;
    int tsincl = block_scan_incl(trun, tid, scan_sh, &ttot);
    int toff = tsincl - trun;
#pragma unroll
    for (int j = 0; j < 16; ++j) cum_sh[base + j] = toff + tincl[j];
    __syncthreads();

    // ---- Phase E: write per-batch tables ----
    int* wbp = ws + (size_t)b * SEG_STRIDE;
    for (int i = tid; i < TIN; i += 256) {
        wbp[i]           = seg_start_sh[i];
        wbp[TIN + i]     = tgt_sh[i];
        wbp[2 * TIN + i] = cum_sh[i];
    }
    if (tid == 0) { wbp[3 * TIN] = n_segs; wbp[3 * TIN + 1] = ttot; }
}

__device__ __forceinline__ void map_concat(int k, const int* cum_sh, const int* wbp,
                                           int n_segs, int& i0, int& i1, float& w) {
    // first index with cum_end[idx] > k  (searchsorted side='right')
    int lo = 0, hi = n_segs;
    while (lo < hi) {
        int mid = (lo + hi) >> 1;
        if (cum_sh[mid] > k) hi = mid; else lo = mid + 1;
    }
    int s = lo;
    if (s > n_segs - 1) s = n_segs - 1;  // safety (k < T_total always)

    int ce = cum_sh[s];
    int tg = wbp[TIN + s];
    int cs = ce - tg;
    int st = wbp[s];
    int en = (s + 1 < n_segs) ? wbp[s + 1] : TIN;
    float L  = (float)(en - st);
    float TL = fmaxf((float)tg, 1.f);
    float src = fmaxf(((float)(k - cs) + 0.5f) * (L / TL) - 0.5f, 0.f);
    float x0 = floorf(src);
    w = src - x0;
    float x1 = fminf(x0 + 1.f, L - 1.f);
    i0 = st + (int)x0;
    i1 = st + (int)x1;
}

__global__ __launch_bounds__(256) void resample_kernel(const float* __restrict__ mel,
                                                       const int* __restrict__ ws,
                                                       float* __restrict__ out) {
    __shared__ int cum_sh[TIN];
    const int b = blockIdx.y;
    const int tid = threadIdx.x;
    const int t = blockIdx.x * 256 + tid;

    const int* wbp = ws + (size_t)b * SEG_STRIDE;
    const int n_segs  = wbp[3 * TIN];
    const int T_total = wbp[3 * TIN + 1];

    for (int i = tid; i < n_segs; i += 256) cum_sh[i] = wbp[2 * TIN + i];
    __syncthreads();

    // second-pass (final resize) coordinates; identity when T_total == T_out
    float sc = fmaxf(((float)t + 0.5f) * ((float)T_total / (float)TOUT) - 0.5f, 0.f);
    int k0 = (int)floorf(sc);
    int k1 = min(k0 + 1, T_total - 1);
    float lam = sc - (float)k0;

    int a0, a1, b0, b1;
    float wa, wb;
    map_concat(k0, cum_sh, wbp, n_segs, a0, a1, wa);
    map_concat(k1, cum_sh, wbp, n_segs, b0, b1, wb);

    const float w_a0 = (1.f - lam) * (1.f - wa);
    const float w_a1 = (1.f - lam) * wa;
    const float w_b0 = lam * (1.f - wb);
    const float w_b1 = lam * wb;

    const float* mb = mel + (size_t)b * FIN * TIN;
    float* ob = out + (size_t)b * FOUT * TOUT;

    // F_in == F_out == 128 -> frequency pass is exact identity (fw == 0)
#pragma unroll 4
    for (int f = 0; f < FOUT; ++f) {
        const float* r = mb + (size_t)f * TIN;
        float v = w_a0 * r[a0] + w_a1 * r[a1] + w_b0 * r[b0] + w_b1 * r[b1];
        ob[(size_t)f * TOUT + t] = v;
    }
}

extern "C" void kernel_launch(void* const* d_in, const int* in_sizes, int n_in,
                              void* d_out, int out_size, void* d_ws, size_t ws_size,
                              hipStream_t stream) {
    const float* mel = (const float*)d_in[0];
    const int* mask  = (const int*)d_in[1];
    float* out = (float*)d_out;
    int* ws = (int*)d_ws;

    seg_kernel<<<NB, 256, 0, stream>>>(mask, ws);

    dim3 grid(TOUT / 256, NB);
    resample_kernel<<<grid, 256, 0, stream>>>(mel, ws, out);
}